// Round 3
// baseline (2482.172 us; speedup 1.0000x reference)
//
#include <hip/hip_runtime.h>

// SentimentLSTM: B=64, T=512, E=128, H=256, V=100000, O=1
// outputs: sig_out[64], hT[1,64,256], cT[1,64,256] -> 32832 f32
//
// ws layout:
//   gx2  bf16 [T][B][1024]  (col-permuted)   67,108,864 B
//   hs   f32  [T][B][H]                      33,554,432 B
//   hx   u64  [2][4][16][128] (data,tag)        131,072 B
//   weff f32  [257]                              1,028 B

#define BATCH 64
#define TSTEPS 512
#define EDIM 128
#define HDIM 256
#define G4H 1024
#define S_H 264  // h_lds row stride in u16 (264/2=132: 132%8=4 -> conflict-free b128)

typedef short bf16x8 __attribute__((ext_vector_type(8)));
typedef short bf16x4 __attribute__((ext_vector_type(4)));
typedef float f32x4 __attribute__((ext_vector_type(4)));

__device__ __forceinline__ unsigned short f2bf(float f) {
  unsigned u = __builtin_bit_cast(unsigned, f);
  return (unsigned short)((u + 0x7fffu + ((u >> 16) & 1u)) >> 16);
}
__device__ __forceinline__ float bf2f(unsigned short h) {
  unsigned u = ((unsigned)h) << 16;
  return __builtin_bit_cast(float, u);
}
__device__ __forceinline__ unsigned pk2(float a, float b) {
  return (unsigned)f2bf(a) | ((unsigned)f2bf(b) << 16);
}
__device__ __forceinline__ float fsig(float x) {
  return __builtin_amdgcn_rcpf(1.f + __expf(-x));
}
__device__ __forceinline__ float ftanh(float x) {
  return 1.f - 2.f * __builtin_amdgcn_rcpf(__expf(2.f * x) + 1.f);
}
// k_gx fragment recipe (elems 0-3 at k0, 4-7 at k0+16); A/B symmetric.
__device__ __forceinline__ bf16x8 ldfrag(const unsigned short* p) {
  bf16x4 a = *(const bf16x4*)p;
  bf16x4 b = *(const bf16x4*)(p + 16);
  return __builtin_shufflevector(a, b, 0, 1, 2, 3, 4, 5, 6, 7);
}
// storage col permutation: orig col c (g*256 + j) -> p*128 + g*32 + (j&31), p=j>>5
__device__ __forceinline__ int colperm(int c) {
  int g = c >> 8, j = c & 255;
  return (j >> 5) * 128 + g * 32 + (j & 31);
}

// ---------------- K1: gx2[t][b][colperm(g)] = emb[x[b,t]] @ W_ih^T + b_ih ---
__global__ __launch_bounds__(256) void k_gx(const int* __restrict__ x,
                                            const float* __restrict__ emb,
                                            const float* __restrict__ Wih,
                                            const float* __restrict__ bih,
                                            unsigned short* __restrict__ gx2) {
  const int t = blockIdx.x;
  const int g0 = blockIdx.y * 64;
  const int tid = threadIdx.x;
  __shared__ unsigned short Al[64 * 136];
  __shared__ unsigned short Bl[64 * 136];
  __shared__ int tok[64];
  if (tid < 64) tok[tid] = x[tid * TSTEPS + t];
  __syncthreads();
  {
    const int r = tid >> 2, c0 = (tid & 3) * 32;
    const float* asrc = emb + (size_t)tok[r] * EDIM + c0;
    const float* bsrc = Wih + (size_t)(g0 + r) * EDIM + c0;
#pragma unroll
    for (int s = 0; s < 32; s += 8) {
      float4 a0 = *(const float4*)(asrc + s);
      float4 a1 = *(const float4*)(asrc + s + 4);
      uint4 pa = {pk2(a0.x, a0.y), pk2(a0.z, a0.w), pk2(a1.x, a1.y), pk2(a1.z, a1.w)};
      *(uint4*)&Al[r * 136 + c0 + s] = pa;
      float4 b0 = *(const float4*)(bsrc + s);
      float4 b1 = *(const float4*)(bsrc + s + 4);
      uint4 pb = {pk2(b0.x, b0.y), pk2(b0.z, b0.w), pk2(b1.x, b1.y), pk2(b1.z, b1.w)};
      *(uint4*)&Bl[r * 136 + c0 + s] = pb;
    }
  }
  __syncthreads();
  const int lane = tid & 63, w = tid >> 6;
  const int lo = lane & 15, hi = lane >> 4;
  const int mb = (w & 1) * 32, nb = (w >> 1) * 32;
  f32x4 acc[2][2];
#pragma unroll
  for (int j = 0; j < 2; ++j) {
    float bv = bih[g0 + nb + j * 16 + lo];
    acc[0][j] = (f32x4){bv, bv, bv, bv};
    acc[1][j] = acc[0][j];
  }
#pragma unroll
  for (int kk = 0; kk < 4; ++kk) {
    bf16x8 af0 = ldfrag(&Al[(mb + lo) * 136 + kk * 32 + hi * 4]);
    bf16x8 af1 = ldfrag(&Al[(mb + 16 + lo) * 136 + kk * 32 + hi * 4]);
    bf16x8 bf0 = ldfrag(&Bl[(nb + lo) * 136 + kk * 32 + hi * 4]);
    bf16x8 bf1 = ldfrag(&Bl[(nb + 16 + lo) * 136 + kk * 32 + hi * 4]);
    acc[0][0] = __builtin_amdgcn_mfma_f32_16x16x32_bf16(af0, bf0, acc[0][0], 0, 0, 0);
    acc[0][1] = __builtin_amdgcn_mfma_f32_16x16x32_bf16(af0, bf1, acc[0][1], 0, 0, 0);
    acc[1][0] = __builtin_amdgcn_mfma_f32_16x16x32_bf16(af1, bf0, acc[1][0], 0, 0, 0);
    acc[1][1] = __builtin_amdgcn_mfma_f32_16x16x32_bf16(af1, bf1, acc[1][1], 0, 0, 0);
  }
#pragma unroll
  for (int i = 0; i < 2; ++i)
#pragma unroll
    for (int j = 0; j < 2; ++j)
#pragma unroll
      for (int r = 0; r < 4; ++r) {
        int m = mb + i * 16 + hi * 4 + r;
        int col = g0 + nb + j * 16 + lo;
        gx2[(size_t)(t * BATCH + m) * G4H + colperm(col)] = f2bf(acc[i][j][r]);
      }
}

// ---------------- K2: the LSTM recurrence ----------------------------------
// 4 groups x 8 blocks; block owns 32 units x 4 gates (128 W rows) in VGPRs.
// Wave w owns units j0+w*4..+3, all gates (16 C cols). Exchange: (bf16-pair,
// step-tag) u64 stores through the coherent point; consumers poll tags.
// One coherence round trip per step instead of three.
__global__ __launch_bounds__(512) void k_rec(const unsigned short* __restrict__ gx2,
                                             const float* __restrict__ Whh,
                                             const float* __restrict__ bhh,
                                             unsigned long long* __restrict__ hx,
                                             float* __restrict__ hs,
                                             float* __restrict__ out) {
  const int tid = threadIdx.x;
  const int grp = blockIdx.x >> 3, p = blockIdx.x & 7;
  const int b0 = grp * 16, j0 = p * 32;
  const int lane = tid & 63, w = tid >> 6;
  const int lo = lane & 15, hi = lane >> 4;
  const int g = lo >> 2, u = lo & 3;
  const int grow = g * HDIM + j0 + w * 4 + u;      // W_hh row = C col
  const int gcolp = p * 128 + g * 32 + w * 4 + u;  // permuted gx col
  __shared__ unsigned short h_lds[16 * S_H];       // [16 batch][256 k] bf16
  __shared__ float g_scratch[8][16 * 17];          // per-wave transpose pad
  // persistent W fragments, contiguous recipe: wf[kk][e] = W[grow][kk*32+hi*8+e]
  bf16x8 wf[8];
#pragma unroll
  for (int kk = 0; kk < 8; ++kk) {
    const float* wsrc = Whh + (size_t)grow * HDIM + kk * 32 + hi * 8;
    float4 v0 = *(const float4*)wsrc;
    float4 v1 = *(const float4*)(wsrc + 4);
    bf16x8 f;
    f[0] = (short)f2bf(v0.x); f[1] = (short)f2bf(v0.y);
    f[2] = (short)f2bf(v0.z); f[3] = (short)f2bf(v0.w);
    f[4] = (short)f2bf(v1.x); f[5] = (short)f2bf(v1.y);
    f[6] = (short)f2bf(v1.z); f[7] = (short)f2bf(v1.w);
    wf[kk] = f;
  }
  const float bhv = bhh[grow];
  const int ub = lane >> 2, uu = lane & 3;  // update-phase roles
  float c_reg = 0.f;
  // h^(0) = 0 in LDS
  for (int i = tid; i < 16 * S_H / 2; i += 512) ((unsigned*)h_lds)[i] = 0u;
  // prefetch gx for t=0
  unsigned short gxr[4];
#pragma unroll
  for (int r = 0; r < 4; ++r)
    gxr[r] = gx2[(size_t)(b0 + hi * 4 + r) * G4H + gcolp];
  __syncthreads();
  for (int t = 0; t < TSTEPS; ++t) {
    // C init = gx + b_hh  (C map: row=batch=hi*4+r, col=lo)
    f32x4 acc0, acc1 = (f32x4){0.f, 0.f, 0.f, 0.f};
#pragma unroll
    for (int r = 0; r < 4; ++r) acc0[r] = bf2f(gxr[r]) + bhv;
    // h @ W^T, two dependency chains
#pragma unroll
    for (int kk = 0; kk < 8; kk += 2) {
      bf16x8 a0 = *(const bf16x8*)&h_lds[lo * S_H + kk * 32 + hi * 8];
      bf16x8 a1 = *(const bf16x8*)&h_lds[lo * S_H + (kk + 1) * 32 + hi * 8];
      acc0 = __builtin_amdgcn_mfma_f32_16x16x32_bf16(a0, wf[kk], acc0, 0, 0, 0);
      acc1 = __builtin_amdgcn_mfma_f32_16x16x32_bf16(a1, wf[kk + 1], acc1, 0, 0, 0);
    }
    f32x4 acc = acc0 + acc1;
    // wave-private transpose: (c=g*4+u, batch) -> (batch=ub, unit=uu) roles
#pragma unroll
    for (int r = 0; r < 4; ++r) g_scratch[w][lo * 17 + hi * 4 + r] = acc[r];
    asm volatile("s_waitcnt lgkmcnt(0)" ::: "memory");
    __builtin_amdgcn_sched_barrier(0);
    float gi = g_scratch[w][(0 * 4 + uu) * 17 + ub];
    float gf = g_scratch[w][(1 * 4 + uu) * 17 + ub];
    float gg = g_scratch[w][(2 * 4 + uu) * 17 + ub];
    float go = g_scratch[w][(3 * 4 + uu) * 17 + ub];
    float iv = fsig(gi), fv = fsig(gf), gv = ftanh(gg), ov = fsig(go);
    c_reg = fv * c_reg + iv * gv;
    float hval = ov * ftanh(c_reg);
    const int unit = j0 + w * 4 + uu;
    hs[(size_t)t * (BATCH * HDIM) + (size_t)(b0 + ub) * HDIM + unit] = hval;
    if (t == TSTEPS - 1) {
      out[64 + (b0 + ub) * HDIM + unit] = hval;
      out[64 + BATCH * HDIM + (b0 + ub) * HDIM + unit] = c_reg;
      break;
    }
    // tagged exchange store: (bf16 pair | tag) as one 8B store
    const int par = (t + 1) & 1;
    {
      float hpart = __shfl_xor(hval, 1);
      if (!(lane & 1)) {
        unsigned long long payload =
            ((unsigned long long)(unsigned)(t + 1) << 32) | (unsigned long long)pk2(hval, hpart);
        const int q = p * 16 + w * 2 + (uu >> 1);
        __hip_atomic_store(&hx[((size_t)(par * 4 + grp) * 16 + ub) * 128 + q],
                           payload, __ATOMIC_RELAXED, __HIP_MEMORY_SCOPE_AGENT);
      }
    }
    // prefetch gx for t+1 (plain cached loads)
#pragma unroll
    for (int r = 0; r < 4; ++r)
      gxr[r] = gx2[(size_t)(t + 1) * (BATCH * G4H) +
                   (size_t)(b0 + hi * 4 + r) * G4H + gcolp];
    // poll-reload: each thread owns 4 consecutive (data,tag) pairs
    {
      const int rb = tid >> 5;            // batch 0..15
      const int q0 = (tid & 31) * 4;      // pair base 0..124
      const size_t base = ((size_t)(par * 4 + grp) * 16 + rb) * 128 + q0;
      unsigned long long v0, v1, v2, v3;
      const unsigned wt = (unsigned)(t + 1);
      do {
        v0 = __hip_atomic_load(&hx[base + 0], __ATOMIC_RELAXED, __HIP_MEMORY_SCOPE_AGENT);
        v1 = __hip_atomic_load(&hx[base + 1], __ATOMIC_RELAXED, __HIP_MEMORY_SCOPE_AGENT);
        v2 = __hip_atomic_load(&hx[base + 2], __ATOMIC_RELAXED, __HIP_MEMORY_SCOPE_AGENT);
        v3 = __hip_atomic_load(&hx[base + 3], __ATOMIC_RELAXED, __HIP_MEMORY_SCOPE_AGENT);
      } while ((unsigned)(v0 >> 32) != wt || (unsigned)(v1 >> 32) != wt ||
               (unsigned)(v2 >> 32) != wt || (unsigned)(v3 >> 32) != wt);
      __syncthreads();  // all MFMA reads of h_lds (this step) are done
      uint4 wv = {(unsigned)v0, (unsigned)v1, (unsigned)v2, (unsigned)v3};
      *(uint4*)&((unsigned*)h_lds)[rb * (S_H / 2) + q0] = wv;
    }
    __syncthreads();  // h_lds ready for next step's MFMA
  }
}

// ---------------- K3: w_eff[k] = sum_j Wf[j]*Wm[j][k]; weff[256] = bm.Wf+bf --
__global__ __launch_bounds__(256) void k_weff(const float* __restrict__ Wm,
                                              const float* __restrict__ bm,
                                              const float* __restrict__ Wf,
                                              const float* __restrict__ bfb,
                                              float* __restrict__ weff) {
  const int k = threadIdx.x;
  __shared__ float red[256];
  float acc = 0.f;
#pragma unroll 8
  for (int j = 0; j < 256; ++j) acc += Wf[j] * Wm[j * 256 + k];
  weff[k] = acc;
  red[k] = bm[k] * Wf[k];
  __syncthreads();
  for (int s = 128; s > 0; s >>= 1) {
    if (k < s) red[k] += red[k + s];
    __syncthreads();
  }
  if (k == 0) weff[256] = red[0] + bfb[0];
}

// ---------------- K4: sig_out[b] = mean_t sigmoid(h_t . weff + c0) ----------
__global__ __launch_bounds__(256) void k_sig(const float* __restrict__ hs,
                                             const float* __restrict__ weff,
                                             float* __restrict__ out) {
  const int b = blockIdx.x;
  const int tid = threadIdx.x, lane = tid & 63, w = tid >> 6;
  __shared__ float wlds[4];
  const float4 w4 = *(const float4*)&weff[lane * 4];
  const float c0 = weff[256];
  float acc = 0.f;
  for (int row = w; row < TSTEPS; row += 4) {
    float4 h4 = *(const float4*)&hs[(size_t)row * (BATCH * HDIM) + b * HDIM + lane * 4];
    float s = h4.x * w4.x + h4.y * w4.y + h4.z * w4.z + h4.w * w4.w;
    s += __shfl_xor(s, 1);  s += __shfl_xor(s, 2);  s += __shfl_xor(s, 4);
    s += __shfl_xor(s, 8);  s += __shfl_xor(s, 16); s += __shfl_xor(s, 32);
    acc += fsig(s + c0);
  }
  if (lane == 0) wlds[w] = acc;
  __syncthreads();
  if (tid == 0) out[b] = (wlds[0] + wlds[1] + wlds[2] + wlds[3]) * (1.f / 512.f);
}

extern "C" void kernel_launch(void* const* d_in, const int* in_sizes, int n_in,
                              void* d_out, int out_size, void* d_ws, size_t ws_size,
                              hipStream_t stream) {
  (void)in_sizes; (void)n_in; (void)out_size; (void)ws_size;
  const int* x = (const int*)d_in[0];
  const float* emb = (const float*)d_in[1];
  const float* Wih = (const float*)d_in[2];
  const float* Whh = (const float*)d_in[3];
  const float* bih = (const float*)d_in[4];
  const float* bhh = (const float*)d_in[5];
  const float* Wm  = (const float*)d_in[6];
  const float* bm  = (const float*)d_in[7];
  const float* Wf  = (const float*)d_in[8];
  const float* bf  = (const float*)d_in[9];
  float* out = (float*)d_out;
  char* ws = (char*)d_ws;
  const size_t gx_bytes = (size_t)TSTEPS * BATCH * G4H * 2;   // 67,108,864
  const size_t hs_bytes = (size_t)TSTEPS * BATCH * HDIM * 4;  // 33,554,432
  const size_t hx_bytes = (size_t)2 * 4 * 16 * 128 * 8;       // 131,072
  unsigned short* gx2 = (unsigned short*)ws;
  float* hs = (float*)(ws + gx_bytes);
  unsigned long long* hx = (unsigned long long*)(ws + gx_bytes + hs_bytes);
  float* weff = (float*)(ws + gx_bytes + hs_bytes + hx_bytes);
  hipMemsetAsync(hx, 0, hx_bytes, stream);  // tags must start at 0 every launch
  k_gx<<<dim3(512, 16), 256, 0, stream>>>(x, emb, Wih, bih, gx2);
  k_weff<<<1, 256, 0, stream>>>(Wm, bm, Wf, bf, weff);
  k_rec<<<32, 512, 0, stream>>>(gx2, Whh, bhh, hx, hs, out);
  k_sig<<<64, 256, 0, stream>>>(hs, weff, out);
}

// Round 4
// 1248.657 us; speedup vs baseline: 1.9879x; 1.9879x over previous
//
#include <hip/hip_runtime.h>

// SentimentLSTM: B=64, T=512, E=128, H=256, V=100000, O=1
// outputs: sig_out[64], hT[1,64,256], cT[1,64,256] -> 32832 f32
//
// k_rec decomposition: 8 blocks = 4 groups x 2 halves.
//   block (grp, half): batches grp*16..+15, units half*128..+127, ALL 4 gates.
//   W slice 512 rows x 256 = 256 KB bf16, fully VGPR-resident (128 regs/lane).
//   Wave w owns units half*128 + w*16 + lo (gate-major tiles) -> cell update
//   is lane-local (i,f,g,o land in the same lane). Pairwise tagged exchange.
//
// ws layout:
//   gx3  bf16 [T][8 bp][8 w][64 lane][16]   67,108,864 B  (lane-major)
//   hs   bf16 [T][B][H]                     16,777,216 B
//   hx   u64  [2 par][8 bp][1024]              131,072 B
//   weff f32  [257]                              1,028 B

#define BATCH 64
#define TSTEPS 512
#define EDIM 128
#define HDIM 256
#define G4H 1024

typedef short bf16x8 __attribute__((ext_vector_type(8)));
typedef short bf16x4 __attribute__((ext_vector_type(4)));
typedef float f32x4 __attribute__((ext_vector_type(4)));

__device__ __forceinline__ unsigned short f2bf(float f) {
  unsigned u = __builtin_bit_cast(unsigned, f);
  return (unsigned short)((u + 0x7fffu + ((u >> 16) & 1u)) >> 16);
}
__device__ __forceinline__ float bf2f(unsigned short h) {
  unsigned u = ((unsigned)h) << 16;
  return __builtin_bit_cast(float, u);
}
__device__ __forceinline__ unsigned pk2(float a, float b) {
  return (unsigned)f2bf(a) | ((unsigned)f2bf(b) << 16);
}
__device__ __forceinline__ float fsig(float x) {
  return __builtin_amdgcn_rcpf(1.f + __expf(-x));
}
__device__ __forceinline__ float ftanh(float x) {
  return 1.f - 2.f * __builtin_amdgcn_rcpf(__expf(2.f * x) + 1.f);
}
__device__ __forceinline__ bf16x8 ldfrag(const unsigned short* p) {
  bf16x4 a = *(const bf16x4*)p;
  bf16x4 b = *(const bf16x4*)(p + 16);
  return __builtin_shufflevector(a, b, 0, 1, 2, 3, 4, 5, 6, 7);
}

// ---------------- K1: gx3[lane-major layout] = emb[x] @ W_ih^T + b_ih ------
__global__ __launch_bounds__(256) void k_gx(const int* __restrict__ x,
                                            const float* __restrict__ emb,
                                            const float* __restrict__ Wih,
                                            const float* __restrict__ bih,
                                            unsigned short* __restrict__ gx3) {
  const int t = blockIdx.x;
  const int g0 = blockIdx.y * 64;
  const int tid = threadIdx.x;
  __shared__ unsigned short Al[64 * 136];
  __shared__ unsigned short Bl[64 * 136];
  __shared__ int tok[64];
  if (tid < 64) tok[tid] = x[tid * TSTEPS + t];
  __syncthreads();
  {
    const int r = tid >> 2, c0 = (tid & 3) * 32;
    const float* asrc = emb + (size_t)tok[r] * EDIM + c0;
    const float* bsrc = Wih + (size_t)(g0 + r) * EDIM + c0;
#pragma unroll
    for (int s = 0; s < 32; s += 8) {
      float4 a0 = *(const float4*)(asrc + s);
      float4 a1 = *(const float4*)(asrc + s + 4);
      uint4 pa = {pk2(a0.x, a0.y), pk2(a0.z, a0.w), pk2(a1.x, a1.y), pk2(a1.z, a1.w)};
      *(uint4*)&Al[r * 136 + c0 + s] = pa;
      float4 b0 = *(const float4*)(bsrc + s);
      float4 b1 = *(const float4*)(bsrc + s + 4);
      uint4 pb = {pk2(b0.x, b0.y), pk2(b0.z, b0.w), pk2(b1.x, b1.y), pk2(b1.z, b1.w)};
      *(uint4*)&Bl[r * 136 + c0 + s] = pb;
    }
  }
  __syncthreads();
  const int lane = tid & 63, w = tid >> 6;
  const int lo = lane & 15, hi = lane >> 4;
  const int mb = (w & 1) * 32, nb = (w >> 1) * 32;
  f32x4 acc[2][2];
#pragma unroll
  for (int jj = 0; jj < 2; ++jj) {
    float bv = bih[g0 + nb + jj * 16 + lo];
    acc[0][jj] = (f32x4){bv, bv, bv, bv};
    acc[1][jj] = acc[0][jj];
  }
#pragma unroll
  for (int kk = 0; kk < 4; ++kk) {
    bf16x8 af0 = ldfrag(&Al[(mb + lo) * 136 + kk * 32 + hi * 4]);
    bf16x8 af1 = ldfrag(&Al[(mb + 16 + lo) * 136 + kk * 32 + hi * 4]);
    bf16x8 bf0 = ldfrag(&Bl[(nb + lo) * 136 + kk * 32 + hi * 4]);
    bf16x8 bf1 = ldfrag(&Bl[(nb + 16 + lo) * 136 + kk * 32 + hi * 4]);
    acc[0][0] = __builtin_amdgcn_mfma_f32_16x16x32_bf16(af0, bf0, acc[0][0], 0, 0, 0);
    acc[0][1] = __builtin_amdgcn_mfma_f32_16x16x32_bf16(af0, bf1, acc[0][1], 0, 0, 0);
    acc[1][0] = __builtin_amdgcn_mfma_f32_16x16x32_bf16(af1, bf0, acc[1][0], 0, 0, 0);
    acc[1][1] = __builtin_amdgcn_mfma_f32_16x16x32_bf16(af1, bf1, acc[1][1], 0, 0, 0);
  }
  // store in k_rec's lane-major layout:
  // idx = (((t*8 + grp*2+half)*8 + w)*64 + bhi*16+lov)*16 + g*4 + br
#pragma unroll
  for (int i = 0; i < 2; ++i)
#pragma unroll
    for (int jj = 0; jj < 2; ++jj)
#pragma unroll
      for (int r = 0; r < 4; ++r) {
        int m = mb + i * 16 + hi * 4 + r;
        int col = g0 + nb + jj * 16 + lo;
        int grp = m >> 4, mm = m & 15;
        int bhi = mm >> 2, br = mm & 3;
        int g = col >> 8, jc = col & 255;
        int halfb = jc >> 7, wv = (jc >> 4) & 7, lov = jc & 15;
        size_t idx = (((size_t)(t * 8 + grp * 2 + halfb) * 8 + wv) * 64 +
                      (bhi * 16 + lov)) * 16 + (g * 4 + br);
        gx3[idx] = f2bf(acc[i][jj][r]);
      }
}

// ---------------- K2: the LSTM recurrence (8 blocks, pairwise exchange) ----
__global__ __launch_bounds__(512) void k_rec(const unsigned short* __restrict__ gx3,
                                             const float* __restrict__ Whh,
                                             const float* __restrict__ bhh,
                                             unsigned long long* __restrict__ hx,
                                             unsigned short* __restrict__ hs,
                                             float* __restrict__ out) {
  const int tid = threadIdx.x;
  const int bp = blockIdx.x;             // 0..7
  const int grp = bp >> 1, half = bp & 1;
  const int b0 = grp * 16;
  const int lane = tid & 63, w = tid >> 6;
  const int lo = lane & 15, hi = lane >> 4;
  const int j = half * 128 + w * 16 + lo;  // this lane's unit (0..255)
  // h_lds k-major: [granule = k>>3][batch][8 elems], stride 136 u16/granule
  __shared__ unsigned short h_lds[2][32 * 136];
  // persistent W: wf[g][kk][e] = Whh[g*256+j][kk*32 + hi*8 + e]  (bf16)
  bf16x8 wf[4][8];
  float bhv[4];
#pragma unroll
  for (int g = 0; g < 4; ++g) {
    const float* wr = Whh + (size_t)(g * 256 + j) * HDIM;
    bhv[g] = bhh[g * 256 + j];
#pragma unroll
    for (int kk = 0; kk < 8; ++kk) {
      const float* p = wr + kk * 32 + hi * 8;
      float4 v0 = *(const float4*)p;
      float4 v1 = *(const float4*)(p + 4);
      bf16x8 f;
      f[0] = (short)f2bf(v0.x); f[1] = (short)f2bf(v0.y);
      f[2] = (short)f2bf(v0.z); f[3] = (short)f2bf(v0.w);
      f[4] = (short)f2bf(v1.x); f[5] = (short)f2bf(v1.y);
      f[6] = (short)f2bf(v1.z); f[7] = (short)f2bf(v1.w);
      wf[g][kk] = f;
    }
  }
  // zero h_lds[0]
  for (int i = tid; i < 32 * 136 / 2; i += 512) ((unsigned*)h_lds[0])[i] = 0u;
  // gx base for this lane; per-t stride = 65536 u16 (=B*4H)
  const unsigned short* gp = gx3 + (((size_t)bp * 8 + w) * 64 + lane) * 16;
  unsigned gw[8];
  {
    uint4 a = *(const uint4*)(gp);
    uint4 b = *(const uint4*)(gp + 8);
    gw[0] = a.x; gw[1] = a.y; gw[2] = a.z; gw[3] = a.w;
    gw[4] = b.x; gw[5] = b.y; gw[6] = b.z; gw[7] = b.w;
  }
  float c[4] = {0.f, 0.f, 0.f, 0.f};
  const int ob = (j >> 3) * 136 + (j & 7);           // own-unit LDS offset part
  const int jp = ((half ^ 1) * 128) + ((tid >> 6) << 4) + (tid & 15);
  const int hip = (tid >> 4) & 3;
  const int pb = (jp >> 3) * 136 + (jp & 7);         // partner-unit LDS offset
  __syncthreads();
  for (int t = 0; t < TSTEPS; ++t) {
    const int cur = t & 1, nxt = cur ^ 1;
    // prefetch gx(t+1): the ONLY vmem before this step's stores
    uint4 gA, gB;
    if (t < TSTEPS - 1) {
      const unsigned short* q = gp + (size_t)(t + 1) * 65536;
      gA = *(const uint4*)(q);
      gB = *(const uint4*)(q + 8);
    }
    // C-init = gx + b_hh   (C row = batch hi*4+r, col = lane's unit, per gate)
    f32x4 acc[4];
#pragma unroll
    for (int g = 0; g < 4; ++g)
#pragma unroll
      for (int r = 0; r < 4; ++r) {
        unsigned word = gw[g * 2 + (r >> 1)];
        unsigned short v = (r & 1) ? (unsigned short)(word >> 16) : (unsigned short)word;
        acc[g][r] = bf2f(v) + bhv[g];
      }
    // h @ W^T : A lane row = batch lo, k = kk*32 + hi*8 + e (matches wf recipe)
#pragma unroll
    for (int kk = 0; kk < 8; ++kk) {
      bf16x8 a = *(const bf16x8*)&h_lds[cur][(kk * 4 + hi) * 136 + lo * 8];
      acc[0] = __builtin_amdgcn_mfma_f32_16x16x32_bf16(a, wf[0][kk], acc[0], 0, 0, 0);
      acc[1] = __builtin_amdgcn_mfma_f32_16x16x32_bf16(a, wf[1][kk], acc[1], 0, 0, 0);
      acc[2] = __builtin_amdgcn_mfma_f32_16x16x32_bf16(a, wf[2][kk], acc[2], 0, 0, 0);
      acc[3] = __builtin_amdgcn_mfma_f32_16x16x32_bf16(a, wf[3][kk], acc[3], 0, 0, 0);
    }
    gw[0] = gA.x; gw[1] = gA.y; gw[2] = gA.z; gw[3] = gA.w;
    gw[4] = gB.x; gw[5] = gB.y; gw[6] = gB.z; gw[7] = gB.w;
    // lane-local cell update: lane holds i,f,g,o for (b=hi*4+r, u=j)
    float hv[4];
    unsigned short hbf[4];
#pragma unroll
    for (int r = 0; r < 4; ++r) {
      float iv = fsig(acc[0][r]);
      float fv = fsig(acc[1][r]);
      float gv = ftanh(acc[2][r]);
      float ov = fsig(acc[3][r]);
      c[r] = fv * c[r] + iv * gv;
      hv[r] = ov * ftanh(c[r]);
      hbf[r] = f2bf(hv[r]);
    }
    if (t == TSTEPS - 1) {
#pragma unroll
      for (int r = 0; r < 4; ++r) {
        const int b = b0 + hi * 4 + r;
        hs[((size_t)t * BATCH + b) * HDIM + j] = hbf[r];
        out[64 + b * HDIM + j] = hv[r];
        out[64 + BATCH * HDIM + b * HDIM + j] = c[r];
      }
      break;
    }
    // tagged exchange: 2 u64 stores (the only vmem before the poll)
    const int par = (t + 1) & 1;
    const unsigned wt = (unsigned)(t + 1);
    {
      const unsigned long long tg = ((unsigned long long)wt) << 32;
      unsigned long long* dst = &hx[((size_t)(par * 8 + bp)) * 1024 + w * 128 + lane * 2];
      __hip_atomic_store(&dst[0], tg | (unsigned long long)pk2(hv[0], hv[1]),
                         __ATOMIC_RELAXED, __HIP_MEMORY_SCOPE_AGENT);
      __hip_atomic_store(&dst[1], tg | (unsigned long long)pk2(hv[2], hv[3]),
                         __ATOMIC_RELAXED, __HIP_MEMORY_SCOPE_AGENT);
    }
    // own half into h_lds[nxt] (k-major)
#pragma unroll
    for (int r = 0; r < 4; ++r) h_lds[nxt][ob + (hi * 4 + r) * 8] = hbf[r];
    // poll partner: exactly 2 u64 loads per thread
    {
      unsigned long long v0, v1;
      unsigned long long* src = &hx[((size_t)(par * 8 + (bp ^ 1))) * 1024 + tid * 2];
      do {
        v0 = __hip_atomic_load(&src[0], __ATOMIC_RELAXED, __HIP_MEMORY_SCOPE_AGENT);
        v1 = __hip_atomic_load(&src[1], __ATOMIC_RELAXED, __HIP_MEMORY_SCOPE_AGENT);
      } while ((unsigned)(v0 >> 32) != wt || (unsigned)(v1 >> 32) != wt);
      h_lds[nxt][pb + (hip * 4 + 0) * 8] = (unsigned short)v0;
      h_lds[nxt][pb + (hip * 4 + 1) * 8] = (unsigned short)(v0 >> 16);
      h_lds[nxt][pb + (hip * 4 + 2) * 8] = (unsigned short)v1;
      h_lds[nxt][pb + (hip * 4 + 3) * 8] = (unsigned short)(v1 >> 16);
    }
    // hs history (bf16) — after the poll, off the detect path
#pragma unroll
    for (int r = 0; r < 4; ++r)
      hs[((size_t)t * BATCH + (b0 + hi * 4 + r)) * HDIM + j] = hbf[r];
    __syncthreads();
  }
}

// ---------------- K3: w_eff[k] = sum_j Wf[j]*Wm[j][k]; weff[256] = bm.Wf+bf --
__global__ __launch_bounds__(256) void k_weff(const float* __restrict__ Wm,
                                              const float* __restrict__ bm,
                                              const float* __restrict__ Wf,
                                              const float* __restrict__ bfb,
                                              float* __restrict__ weff) {
  const int k = threadIdx.x;
  __shared__ float red[256];
  float acc = 0.f;
#pragma unroll 8
  for (int jj = 0; jj < 256; ++jj) acc += Wf[jj] * Wm[jj * 256 + k];
  weff[k] = acc;
  red[k] = bm[k] * Wf[k];
  __syncthreads();
  for (int s = 128; s > 0; s >>= 1) {
    if (k < s) red[k] += red[k + s];
    __syncthreads();
  }
  if (k == 0) weff[256] = red[0] + bfb[0];
}

// ---------------- K4: sig_out[b] = mean_t sigmoid(h_t . weff + c0) ----------
__global__ __launch_bounds__(256) void k_sig(const unsigned short* __restrict__ hs,
                                             const float* __restrict__ weff,
                                             float* __restrict__ out) {
  const int b = blockIdx.x;
  const int tid = threadIdx.x, lane = tid & 63, w = tid >> 6;
  __shared__ float wlds[4];
  const float4 w4 = *(const float4*)&weff[lane * 4];
  const float c0 = weff[256];
  float acc = 0.f;
  for (int row = w; row < TSTEPS; row += 4) {
    const unsigned short* hp = &hs[((size_t)row * BATCH + b) * HDIM + lane * 4];
    ushort4 h4 = *(const ushort4*)hp;
    float s = bf2f(h4.x) * w4.x + bf2f(h4.y) * w4.y +
              bf2f(h4.z) * w4.z + bf2f(h4.w) * w4.w;
    s += __shfl_xor(s, 1);  s += __shfl_xor(s, 2);  s += __shfl_xor(s, 4);
    s += __shfl_xor(s, 8);  s += __shfl_xor(s, 16); s += __shfl_xor(s, 32);
    acc += fsig(s + c0);
  }
  if (lane == 0) wlds[w] = acc;
  __syncthreads();
  if (tid == 0) out[b] = (wlds[0] + wlds[1] + wlds[2] + wlds[3]) * (1.f / 512.f);
}

extern "C" void kernel_launch(void* const* d_in, const int* in_sizes, int n_in,
                              void* d_out, int out_size, void* d_ws, size_t ws_size,
                              hipStream_t stream) {
  (void)in_sizes; (void)n_in; (void)out_size; (void)ws_size;
  const int* x = (const int*)d_in[0];
  const float* emb = (const float*)d_in[1];
  const float* Wih = (const float*)d_in[2];
  const float* Whh = (const float*)d_in[3];
  const float* bih = (const float*)d_in[4];
  const float* bhh = (const float*)d_in[5];
  const float* Wm  = (const float*)d_in[6];
  const float* bm  = (const float*)d_in[7];
  const float* Wf  = (const float*)d_in[8];
  const float* bf  = (const float*)d_in[9];
  float* out = (float*)d_out;
  char* ws = (char*)d_ws;
  const size_t gx_bytes = (size_t)TSTEPS * BATCH * G4H * 2;   // 67,108,864
  const size_t hs_bytes = (size_t)TSTEPS * BATCH * HDIM * 2;  // 16,777,216
  const size_t hx_bytes = (size_t)2 * 8 * 1024 * 8;           // 131,072
  unsigned short* gx3 = (unsigned short*)ws;
  unsigned short* hs = (unsigned short*)(ws + gx_bytes);
  unsigned long long* hx = (unsigned long long*)(ws + gx_bytes + hs_bytes);
  float* weff = (float*)(ws + gx_bytes + hs_bytes + hx_bytes);
  hipMemsetAsync(hx, 0, hx_bytes, stream);  // tags start at 0 every launch
  k_gx<<<dim3(512, 16), 256, 0, stream>>>(x, emb, Wih, bih, gx3);
  k_weff<<<1, 256, 0, stream>>>(Wm, bm, Wf, bf, weff);
  k_rec<<<8, 512, 0, stream>>>(gx3, Whh, bhh, hx, hs, out);
  k_sig<<<64, 256, 0, stream>>>(hs, weff, out);
}